// Round 5
// baseline (290.650 us; speedup 1.0000x reference)
//
#include <hip/hip_runtime.h>
#include <hip/hip_bf16.h>

#define T_SEQ 1024
#define D_MODEL 512
#define N_HEADS 8
#define D_HEAD 64
// 0.125 (1/sqrt(64)) * log2(e): scores computed directly in exp2 domain
#define KSCALE 0.1803368801111244f

typedef unsigned short ushort_t;
typedef short s16x8 __attribute__((ext_vector_type(8)));
typedef float f32x4 __attribute__((ext_vector_type(4)));

__device__ inline f32x4 mfma16(s16x8 a, s16x8 b, f32x4 c) {
    return __builtin_amdgcn_mfma_f32_16x16x32_bf16(a, b, c, 0, 0, 0);
}

__device__ inline ushort_t f2bf(float f) {   // RTNE float->bf16
    union { float f; unsigned u; } v; v.f = f;
    unsigned r = v.u + 0x7FFFu + ((v.u >> 16) & 1u);
    return (ushort_t)(r >> 16);
}
__device__ inline void cvt4(const float4 f, ushort_t* t) {
    t[0] = f2bf(f.x); t[1] = f2bf(f.y); t[2] = f2bf(f.z); t[3] = f2bf(f.w);
}
__device__ inline s16x8 pack8(const ushort_t* t) {
    s16x8 r;
    #pragma unroll
    for (int e = 0; e < 8; ++e) r[e] = (short)t[e];
    return r;
}

// ---------------------------------------------------------------------------
// Pre-cast x (8192x512) and pos_enc (2047x512, row 2047 zeroed) to bf16.
// ---------------------------------------------------------------------------
__global__ __launch_bounds__(256) void cast_inputs(
    const float* __restrict__ x, const float* __restrict__ pos,
    ushort_t* __restrict__ xb, ushort_t* __restrict__ posb)
{
    const size_t N1 = (size_t)8192 * 512;
    size_t e = ((size_t)blockIdx.x * 256 + threadIdx.x) * 8;
    ushort_t tmp[8];
    if (e < N1) {
        const float4* s = (const float4*)(x + e);
        cvt4(s[0], tmp); cvt4(s[1], tmp + 4);
        *(s16x8*)(xb + e) = pack8(tmp);
    } else {
        size_t e2 = e - N1;                 // < 2048*512
        int row = (int)(e2 >> 9);
        if (row < 2047) {
            const float4* s = (const float4*)(pos + e2);
            cvt4(s[0], tmp); cvt4(s[1], tmp + 4);
        } else {
            #pragma unroll
            for (int i = 0; i < 8; ++i) tmp[i] = 0;
        }
        *(s16x8*)(posb + e2) = pack8(tmp);
    }
}

// ---------------------------------------------------------------------------
// Transpose+cast weights: WT[z][n][k] = bf16(W[k][n]), 512x512, z=0..4
// ---------------------------------------------------------------------------
__global__ __launch_bounds__(256) void transpose_cast_w(
    const float* __restrict__ W0, const float* __restrict__ W1,
    const float* __restrict__ W2, const float* __restrict__ W3,
    const float* __restrict__ W4, ushort_t* __restrict__ WT)
{
    const float* W = (blockIdx.z == 0) ? W0 : (blockIdx.z == 1) ? W1
                   : (blockIdx.z == 2) ? W2 : (blockIdx.z == 3) ? W3 : W4;
    __shared__ float T[64][68];
    const int n0 = blockIdx.x * 64, k0 = blockIdx.y * 64;
    const int tid = threadIdx.x;
    const int rr = tid >> 2, cc = (tid & 3) * 16;

    const float* src = W + (size_t)(k0 + rr) * 512 + n0 + cc;
    *(float4*)&T[rr][cc + 0]  = *(const float4*)(src);
    *(float4*)&T[rr][cc + 4]  = *(const float4*)(src + 4);
    *(float4*)&T[rr][cc + 8]  = *(const float4*)(src + 8);
    *(float4*)&T[rr][cc + 12] = *(const float4*)(src + 12);
    __syncthreads();

    ushort_t tmp[16];
    #pragma unroll
    for (int e = 0; e < 16; ++e) tmp[e] = f2bf(T[cc + e][rr]);
    ushort_t* dst = WT + ((size_t)blockIdx.z * 512 + n0 + rr) * 512 + k0 + cc;
    *(s16x8*)dst       = pack8(tmp);
    *(s16x8*)(dst + 8) = pack8(tmp + 8);
}

// ---------------------------------------------------------------------------
// 128x128-tile MFMA GEMM (4 waves, each 64x64 via 4x4 16x16x32 frags), K=512.
// A bf16 [M][512], WTb bf16 [n][k].  Templated fused epilogue:
//  EPI=0: qkv (N=1536; set=col0>>9: Q->Qu/Qv scaled, K->Ko, V->VoT transposed)
//  EPI=1: out fp32 + bias
//  EPI=2: bf16 store (P GEMM)
// ---------------------------------------------------------------------------
template<int EPI>
__global__ __launch_bounds__(256) void gemm128(
    const ushort_t* __restrict__ A, const ushort_t* __restrict__ WTb,
    const float* __restrict__ c0p, const float* __restrict__ c1p,
    const float* __restrict__ c2p, const float* __restrict__ c3p,
    const float* __restrict__ c4p,
    ushort_t* __restrict__ o0, ushort_t* __restrict__ o1,
    ushort_t* __restrict__ o2, ushort_t* __restrict__ o3,
    float* __restrict__ of)
{
    const int tid = threadIdx.x;
    const int col0 = blockIdx.x * 128;
    const int row0 = blockIdx.y * 128;
    const int w = tid >> 6, lane = tid & 63;
    const int quad = lane >> 4, lanelo = lane & 15;
    const int wr = w >> 1, wc = w & 1;
    const int sr = tid >> 1, sc = (tid & 1) * 32;

    __shared__ ushort_t As[128][72];
    __shared__ ushort_t Bs[128][72];

    f32x4 acc[4][4] = {};

    for (int k0 = 0; k0 < 512; k0 += 64) {
        __syncthreads();
        {
            const ushort_t* ap = A + (size_t)(row0 + sr) * 512 + k0 + sc;
            *(s16x8*)&As[sr][sc +  0] = *(const s16x8*)(ap +  0);
            *(s16x8*)&As[sr][sc +  8] = *(const s16x8*)(ap +  8);
            *(s16x8*)&As[sr][sc + 16] = *(const s16x8*)(ap + 16);
            *(s16x8*)&As[sr][sc + 24] = *(const s16x8*)(ap + 24);
            const ushort_t* wp = WTb + (size_t)(col0 + sr) * 512 + k0 + sc;
            *(s16x8*)&Bs[sr][sc +  0] = *(const s16x8*)(wp +  0);
            *(s16x8*)&Bs[sr][sc +  8] = *(const s16x8*)(wp +  8);
            *(s16x8*)&Bs[sr][sc + 16] = *(const s16x8*)(wp + 16);
            *(s16x8*)&Bs[sr][sc + 24] = *(const s16x8*)(wp + 24);
        }
        __syncthreads();

        #pragma unroll
        for (int ks = 0; ks < 2; ++ks) {
            s16x8 af[4], bf[4];
            #pragma unroll
            for (int i = 0; i < 4; ++i)
                af[i] = *(const s16x8*)&As[64 * wr + 16 * i + lanelo][ks * 32 + quad * 8];
            #pragma unroll
            for (int j = 0; j < 4; ++j)
                bf[j] = *(const s16x8*)&Bs[64 * wc + 16 * j + lanelo][ks * 32 + quad * 8];
            #pragma unroll
            for (int i = 0; i < 4; ++i)
                #pragma unroll
                for (int j = 0; j < 4; ++j)
                    acc[i][j] = mfma16(af[i], bf[j], acc[i][j]);
        }
    }

    if (EPI == 0) {
        const int set = col0 >> 9;               // 0=Q,1=K,2=V (tile never straddles)
        const int cbase = (col0 & 511) + 64 * wc;
        if (set == 0) {
            #pragma unroll
            for (int j = 0; j < 4; ++j) {
                int c = cbase + 16 * j + lanelo;
                float vbq = c0p[c], vu = c3p[c], vv = c4p[c];
                #pragma unroll
                for (int i = 0; i < 4; ++i)
                    #pragma unroll
                    for (int r = 0; r < 4; ++r) {
                        int row = row0 + 64 * wr + 16 * i + 4 * quad + r;
                        size_t o = (size_t)row * 512 + c;
                        float aq = acc[i][j][r] + vbq;
                        o0[o] = f2bf((aq + vu) * KSCALE);
                        o1[o] = f2bf((aq + vv) * KSCALE);
                    }
            }
        } else if (set == 1) {
            #pragma unroll
            for (int j = 0; j < 4; ++j) {
                int c = cbase + 16 * j + lanelo;
                float vbk = c1p[c];
                #pragma unroll
                for (int i = 0; i < 4; ++i)
                    #pragma unroll
                    for (int r = 0; r < 4; ++r) {
                        int row = row0 + 64 * wr + 16 * i + 4 * quad + r;
                        o2[(size_t)row * 512 + c] = f2bf(acc[i][j][r] + vbk);
                    }
            }
        } else {
            const int b_idx = row0 >> 10;
            #pragma unroll
            for (int j = 0; j < 4; ++j) {
                int c = cbase + 16 * j + lanelo;
                int hh = c >> 6, d = c & 63;
                float vbb = c2p[c];
                #pragma unroll
                for (int i = 0; i < 4; ++i) {
                    int t = (row0 & 1023) + 64 * wr + 16 * i + 4 * quad;
                    ushort4 vp;
                    vp.x = f2bf(acc[i][j][0] + vbb);
                    vp.y = f2bf(acc[i][j][1] + vbb);
                    vp.z = f2bf(acc[i][j][2] + vbb);
                    vp.w = f2bf(acc[i][j][3] + vbb);
                    *(ushort4*)(o3 + ((size_t)((b_idx * 8 + hh) * 64 + d)) * 1024 + t) = vp;
                }
            }
        }
    } else if (EPI == 1) {
        #pragma unroll
        for (int j = 0; j < 4; ++j) {
            int c = col0 + 64 * wc + 16 * j + lanelo;
            float vb = c0p[c];
            #pragma unroll
            for (int i = 0; i < 4; ++i)
                #pragma unroll
                for (int r = 0; r < 4; ++r) {
                    int row = row0 + 64 * wr + 16 * i + 4 * quad + r;
                    of[(size_t)row * 512 + c] = acc[i][j][r] + vb;
                }
        }
    } else {
        #pragma unroll
        for (int j = 0; j < 4; ++j) {
            int c = col0 + 64 * wc + 16 * j + lanelo;
            #pragma unroll
            for (int i = 0; i < 4; ++i)
                #pragma unroll
                for (int r = 0; r < 4; ++r) {
                    int row = row0 + 64 * wr + 16 * i + 4 * quad + r;
                    o0[(size_t)row * 512 + c] = f2bf(acc[i][j][r]);
                }
        }
    }
}

// ---------------------------------------------------------------------------
// MFMA flash attention, fused relative shift, NO-MAX softmax (exact: scores
// bounded ~|9| in exp2 domain; softmax is shift-invariant so raw exp is safe).
// Block: (64 q-rows, h, b); wave w rows [16w,+16).
// K and V^T MFMA B-fragments read directly from global (contiguous 16B/lane);
// only the 128-row P window + probs live in LDS (27.6 KB).
// ---------------------------------------------------------------------------
__global__ __launch_bounds__(256, 4) void attn_mfma(
    const ushort_t* __restrict__ Qu, const ushort_t* __restrict__ Qv,
    const ushort_t* __restrict__ Kb, const ushort_t* __restrict__ VT,
    const ushort_t* __restrict__ Pb,
    ushort_t* __restrict__ AOb)
{
    const int tid = threadIdx.x;
    const int t0 = blockIdx.x * 64;
    const int h  = blockIdx.y;
    const int b  = blockIdx.z;
    const int w = tid >> 6, lane = tid & 63;
    const int quad = lane >> 4, lanelo = lane & 15;

    __shared__ ushort_t Pt[128][72];    // 18432 B
    __shared__ ushort_t Ps[64][72];     //  9216 B  -> 27648 B total

    const size_t qrow = (size_t)(b * T_SEQ + t0 + 16 * w + lanelo) * 512 + h * 64;
    s16x8 qu[2], qv[2];
    qu[0] = *(const s16x8*)(Qu + qrow + quad * 8);
    qu[1] = *(const s16x8*)(Qu + qrow + 32 + quad * 8);
    qv[0] = *(const s16x8*)(Qv + qrow + quad * 8);
    qv[1] = *(const s16x8*)(Qv + qrow + 32 + quad * 8);

    f32x4 acc_o[4] = {};
    float l_part[4] = {0.f, 0.f, 0.f, 0.f};

    const int u_base = lanelo + 63 - 4 * quad;       // u = u_base - r in [48,78]
    const ushort_t* VTbh = VT + ((size_t)((b * 8 + h) * 64)) * 1024;
    const ushort_t* Kbh  = Kb + (size_t)b * T_SEQ * 512 + (size_t)h * 64;

    const int pr_r = tid >> 1;           // 0..127
    const int pr_c = (tid & 1) * 32;

    for (int s0 = 0; s0 < T_SEQ; s0 += 64) {
        const int pr0 = s0 - t0 + 960;               // [0,1920]
        __syncthreads();
        {   // stage 128-row P window
            const ushort_t* gp = Pb + (size_t)(pr0 + pr_r) * 512 + h * 64 + pr_c;
            *(s16x8*)&Pt[pr_r][pr_c +  0] = *(const s16x8*)(gp +  0);
            *(s16x8*)&Pt[pr_r][pr_c +  8] = *(const s16x8*)(gp +  8);
            *(s16x8*)&Pt[pr_r][pr_c + 16] = *(const s16x8*)(gp + 16);
            *(s16x8*)&Pt[pr_r][pr_c + 24] = *(const s16x8*)(gp + 24);
        }
        __syncthreads();

        f32x4 acc_c[4] = {};
        f32x4 acc_g[5] = {};
        #pragma unroll
        for (int ks = 0; ks < 2; ++ks) {
            #pragma unroll
            for (int tn = 0; tn < 4; ++tn) {   // K B-frag direct from global
                s16x8 kf = *(const s16x8*)(Kbh
                    + (size_t)(s0 + 16 * tn + lanelo) * 512 + ks * 32 + quad * 8);
                acc_c[tn] = mfma16(qu[ks], kf, acc_c[tn]);
            }
            #pragma unroll
            for (int i = 0; i < 5; ++i) {      // jt = 3 - w + i
                s16x8 pf = *(const s16x8*)&Pt[(3 - w + i) * 16 + lanelo][ks * 32 + quad * 8];
                acc_g[i] = mfma16(qv[ks], pf, acc_g[i]);
            }
        }

        // band extraction + exp2 (no max subtraction; softmax shift-invariant)
        float p[4][4];
        #pragma unroll
        for (int r = 0; r < 4; ++r) {
            int u = u_base - r;
            int srcl = (quad << 4) | (u & 15);
            bool hi = (u >= 64);
            #pragma unroll
            for (int tn = 0; tn < 4; ++tn) {
                float v0 = __shfl(acc_g[tn][r], srcl);
                float v1 = __shfl(acc_g[tn + 1][r], srcl);
                float e = __builtin_amdgcn_exp2f(acc_c[tn][r] + (hi ? v1 : v0));
                p[tn][r] = e;
                l_part[r] += e;
            }
        }
        #pragma unroll
        for (int tn = 0; tn < 4; ++tn)
            #pragma unroll
            for (int r = 0; r < 4; ++r)
                Ps[16 * w + 4 * quad + r][tn * 16 + lanelo] = f2bf(p[tn][r]);
        asm volatile("s_waitcnt lgkmcnt(0)" ::: "memory");

        // PV: A = probs (wave-private Ps rows), B = V^T direct from global
        #pragma unroll
        for (int ks = 0; ks < 2; ++ks) {
            s16x8 af = *(const s16x8*)&Ps[16 * w + lanelo][ks * 32 + quad * 8];
            #pragma unroll
            for (int dt = 0; dt < 4; ++dt) {
                s16x8 vb = *(const s16x8*)(VTbh
                    + (size_t)(16 * dt + lanelo) * 1024 + s0 + ks * 32 + quad * 8);
                acc_o[dt] = mfma16(af, vb, acc_o[dt]);
            }
        }
    }

    // single end-of-kernel l reduction (16 lanes per row group)
    float inv[4];
    #pragma unroll
    for (int r = 0; r < 4; ++r) {
        float l = l_part[r];
        l += __shfl_xor(l, 1);
        l += __shfl_xor(l, 2);
        l += __shfl_xor(l, 4);
        l += __shfl_xor(l, 8);
        inv[r] = 1.0f / l;
    }

    // epilogue: stage O into Ps (bf16), then coalesced vector stores
    __syncthreads();
    #pragma unroll
    for (int r = 0; r < 4; ++r)
        #pragma unroll
        for (int dt = 0; dt < 4; ++dt)
            Ps[16 * w + 4 * quad + r][dt * 16 + lanelo] = f2bf(acc_o[dt][r] * inv[r]);
    __syncthreads();
    {
        const int esr = tid >> 2, esc = (tid & 3) * 16;
        ushort_t* dst = AOb + (size_t)(b * T_SEQ + t0 + esr) * 512 + h * 64 + esc;
        *(s16x8*)dst       = *(const s16x8*)&Ps[esr][esc];
        *(s16x8*)(dst + 8) = *(const s16x8*)&Ps[esr][esc + 8];
    }
}

// ---------------------------------------------------------------------------
extern "C" void kernel_launch(void* const* d_in, const int* in_sizes, int n_in,
                              void* d_out, int out_size, void* d_ws, size_t ws_size,
                              hipStream_t stream) {
    const float* x       = (const float*)d_in[0];
    const float* pos_enc = (const float*)d_in[1];
    const float* Wq      = (const float*)d_in[2];
    const float* bq      = (const float*)d_in[3];
    const float* Wk      = (const float*)d_in[4];
    const float* bk      = (const float*)d_in[5];
    const float* Wv      = (const float*)d_in[6];
    const float* bv      = (const float*)d_in[7];
    const float* Wpos    = (const float*)d_in[8];
    const float* pbu     = (const float*)d_in[9];
    const float* pbv     = (const float*)d_in[10];
    const float* Wo      = (const float*)d_in[11];
    const float* bo      = (const float*)d_in[12];
    float* out = (float*)d_out;

    const size_t M  = 8 * T_SEQ;                 // 8192
    const size_t SZ = M * D_MODEL;               // 4,194,304

    char* ws = (char*)d_ws;
    ushort_t* xb   = (ushort_t*)ws;              ws += SZ * 2;
    ushort_t* posb = (ushort_t*)ws;              ws += (size_t)2048 * 512 * 2;
    ushort_t* Qu_b = (ushort_t*)ws;              ws += SZ * 2;
    ushort_t* Qv_b = (ushort_t*)ws;              ws += SZ * 2;
    ushort_t* K_b  = (ushort_t*)ws;              ws += SZ * 2;
    ushort_t* VT_b = (ushort_t*)ws;              ws += SZ * 2;
    ushort_t* P_b  = (ushort_t*)ws;              ws += (size_t)2048 * 512 * 2;
    ushort_t* WT   = (ushort_t*)ws;              ws += (size_t)5 * 512 * 512 * 2;
    ushort_t* AOb  = (ushort_t*)ws;              ws += SZ * 2;

    dim3 blk(256);

    hipLaunchKernelGGL(cast_inputs, dim3(2560), blk, 0, stream, x, pos_enc, xb, posb);

    hipLaunchKernelGGL(transpose_cast_w, dim3(8, 8, 5), blk, 0, stream,
                       Wq, Wk, Wv, Wpos, Wo, WT);

    hipLaunchKernelGGL((gemm128<0>), dim3(12, 64), blk, 0, stream,
                       xb, WT, bq, bk, bv, pbu, pbv,
                       Qu_b, Qv_b, K_b, VT_b, (float*)nullptr);

    hipLaunchKernelGGL((gemm128<2>), dim3(4, 16), blk, 0, stream,
                       posb, WT + (size_t)3 * 512 * 512,
                       (const float*)nullptr, (const float*)nullptr, (const float*)nullptr,
                       (const float*)nullptr, (const float*)nullptr,
                       P_b, (ushort_t*)nullptr, (ushort_t*)nullptr, (ushort_t*)nullptr,
                       (float*)nullptr);

    hipLaunchKernelGGL(attn_mfma, dim3(16, 8, 8), blk, 0, stream,
                       Qu_b, Qv_b, K_b, VT_b, P_b, AOb);

    hipLaunchKernelGGL((gemm128<1>), dim3(4, 64), blk, 0, stream,
                       AOb, WT + (size_t)4 * 512 * 512,
                       bo, (const float*)nullptr, (const float*)nullptr,
                       (const float*)nullptr, (const float*)nullptr,
                       (ushort_t*)nullptr, (ushort_t*)nullptr, (ushort_t*)nullptr,
                       (ushort_t*)nullptr, out);
}

// Round 6
// 240.333 us; speedup vs baseline: 1.2094x; 1.2094x over previous
//
#include <hip/hip_runtime.h>
#include <hip/hip_bf16.h>

#define T_SEQ 1024
#define D_MODEL 512
#define N_HEADS 8
#define D_HEAD 64
// 0.125 (1/sqrt(64)) * log2(e): scores computed directly in exp2 domain
#define KSCALE 0.1803368801111244f

typedef unsigned short ushort_t;
typedef short s16x8 __attribute__((ext_vector_type(8)));
typedef float f32x4 __attribute__((ext_vector_type(4)));

__device__ inline f32x4 mfma16(s16x8 a, s16x8 b, f32x4 c) {
    return __builtin_amdgcn_mfma_f32_16x16x32_bf16(a, b, c, 0, 0, 0);
}

__device__ inline ushort_t f2bf(float f) {   // RTNE float->bf16
    union { float f; unsigned u; } v; v.f = f;
    unsigned r = v.u + 0x7FFFu + ((v.u >> 16) & 1u);
    return (ushort_t)(r >> 16);
}
__device__ inline void cvt4(const float4 f, ushort_t* t) {
    t[0] = f2bf(f.x); t[1] = f2bf(f.y); t[2] = f2bf(f.z); t[3] = f2bf(f.w);
}
__device__ inline s16x8 pack8(const ushort_t* t) {
    s16x8 r;
    #pragma unroll
    for (int e = 0; e < 8; ++e) r[e] = (short)t[e];
    return r;
}

// ---------------------------------------------------------------------------
// prep: blocks [0,2560) cast x->xb + pos->posb (row 2047 zeroed);
//       blocks [2560,2880) transpose+cast the 5 weight matrices into WT.
// ---------------------------------------------------------------------------
__global__ __launch_bounds__(256) void prep(
    const float* __restrict__ x, const float* __restrict__ pos,
    const float* __restrict__ W0, const float* __restrict__ W1,
    const float* __restrict__ W2, const float* __restrict__ W3,
    const float* __restrict__ W4,
    ushort_t* __restrict__ xb, ushort_t* __restrict__ posb,
    ushort_t* __restrict__ WT)
{
    __shared__ float T[64][68];
    const int bx = blockIdx.x;
    const int tid = threadIdx.x;
    if (bx < 2560) {
        const size_t N1 = (size_t)8192 * 512;
        size_t e = ((size_t)bx * 256 + tid) * 8;
        ushort_t tmp[8];
        if (e < N1) {
            const float4* s = (const float4*)(x + e);
            cvt4(s[0], tmp); cvt4(s[1], tmp + 4);
            *(s16x8*)(xb + e) = pack8(tmp);
        } else {
            size_t e2 = e - N1;                 // < 2048*512
            int row = (int)(e2 >> 9);
            if (row < 2047) {
                const float4* s = (const float4*)(pos + e2);
                cvt4(s[0], tmp); cvt4(s[1], tmp + 4);
            } else {
                #pragma unroll
                for (int i = 0; i < 8; ++i) tmp[i] = 0;
            }
            *(s16x8*)(posb + e2) = pack8(tmp);
        }
    } else {
        const int bz = bx - 2560;               // 0..319
        const int z = bz >> 6;                  // 0..4
        const int rem = bz & 63;
        const int n0 = (rem & 7) * 64, k0 = (rem >> 3) * 64;
        const float* W = (z == 0) ? W0 : (z == 1) ? W1
                       : (z == 2) ? W2 : (z == 3) ? W3 : W4;
        const int rr = tid >> 2, cc = (tid & 3) * 16;

        const float* src = W + (size_t)(k0 + rr) * 512 + n0 + cc;
        *(float4*)&T[rr][cc + 0]  = *(const float4*)(src);
        *(float4*)&T[rr][cc + 4]  = *(const float4*)(src + 4);
        *(float4*)&T[rr][cc + 8]  = *(const float4*)(src + 8);
        *(float4*)&T[rr][cc + 12] = *(const float4*)(src + 12);
        __syncthreads();

        ushort_t tmp[16];
        #pragma unroll
        for (int e = 0; e < 16; ++e) tmp[e] = f2bf(T[cc + e][rr]);
        ushort_t* dst = WT + ((size_t)z * 512 + n0 + rr) * 512 + k0 + cc;
        *(s16x8*)dst       = pack8(tmp);
        *(s16x8*)(dst + 8) = pack8(tmp + 8);
    }
}

// ---------------------------------------------------------------------------
// Fused QKV + P GEMM, 128x128 tiles, 4 waves (each 64x64 via 4x4 frags), K=512.
// Grid (13, 64): bx<12 -> qkv (N=1536, set=col0>>9); bx==12 -> P GEMM,
// with by encoding (row-tile = by>>2 of 16, col-tile = by&3 of 4), M=2048.
// Q epilogue: Qu=(acc+bq+pbu)*KSCALE, Qv=(acc+bq+pbv)*KSCALE (bf16).
// V epilogue writes transposed VoT[((b*8+h)*64+d)][t]  (ushort4 t-packed).
// ---------------------------------------------------------------------------
__global__ __launch_bounds__(256) void gemm_qkvp(
    const ushort_t* __restrict__ xb, const ushort_t* __restrict__ posb,
    const ushort_t* __restrict__ WT,
    const float* __restrict__ bq, const float* __restrict__ bk,
    const float* __restrict__ bv,
    const float* __restrict__ pbu, const float* __restrict__ pbv,
    ushort_t* __restrict__ Qu, ushort_t* __restrict__ Qv,
    ushort_t* __restrict__ Ko, ushort_t* __restrict__ VoT,
    ushort_t* __restrict__ Po)
{
    const int tid = threadIdx.x;
    const bool is_p = (blockIdx.x == 12);
    int row0, col0;
    const ushort_t* A;
    const ushort_t* B;
    if (is_p) {
        row0 = ((int)blockIdx.y >> 2) * 128;     // 0..1920
        col0 = ((int)blockIdx.y & 3) * 128;      // 0..384
        A = posb;
        B = WT + (size_t)3 * 512 * 512;
    } else {
        row0 = blockIdx.y * 128;
        col0 = blockIdx.x * 128;
        A = xb;
        B = WT;                                  // col0 spans 0..1535 across sets
    }
    const int w = tid >> 6, lane = tid & 63;
    const int quad = lane >> 4, lanelo = lane & 15;
    const int wr = w >> 1, wc = w & 1;
    const int sr = tid >> 1, sc = (tid & 1) * 32;

    __shared__ ushort_t As[128][72];
    __shared__ ushort_t Bs[128][72];

    f32x4 acc[4][4] = {};

    for (int k0 = 0; k0 < 512; k0 += 64) {
        __syncthreads();
        {
            const ushort_t* ap = A + (size_t)(row0 + sr) * 512 + k0 + sc;
            *(s16x8*)&As[sr][sc +  0] = *(const s16x8*)(ap +  0);
            *(s16x8*)&As[sr][sc +  8] = *(const s16x8*)(ap +  8);
            *(s16x8*)&As[sr][sc + 16] = *(const s16x8*)(ap + 16);
            *(s16x8*)&As[sr][sc + 24] = *(const s16x8*)(ap + 24);
            const ushort_t* wp = B + (size_t)(col0 + sr) * 512 + k0 + sc;
            *(s16x8*)&Bs[sr][sc +  0] = *(const s16x8*)(wp +  0);
            *(s16x8*)&Bs[sr][sc +  8] = *(const s16x8*)(wp +  8);
            *(s16x8*)&Bs[sr][sc + 16] = *(const s16x8*)(wp + 16);
            *(s16x8*)&Bs[sr][sc + 24] = *(const s16x8*)(wp + 24);
        }
        __syncthreads();

        #pragma unroll
        for (int ks = 0; ks < 2; ++ks) {
            s16x8 af[4], bf[4];
            #pragma unroll
            for (int i = 0; i < 4; ++i)
                af[i] = *(const s16x8*)&As[64 * wr + 16 * i + lanelo][ks * 32 + quad * 8];
            #pragma unroll
            for (int j = 0; j < 4; ++j)
                bf[j] = *(const s16x8*)&Bs[64 * wc + 16 * j + lanelo][ks * 32 + quad * 8];
            #pragma unroll
            for (int i = 0; i < 4; ++i)
                #pragma unroll
                for (int j = 0; j < 4; ++j)
                    acc[i][j] = mfma16(af[i], bf[j], acc[i][j]);
        }
    }

    if (is_p) {
        #pragma unroll
        for (int j = 0; j < 4; ++j) {
            int c = col0 + 64 * wc + 16 * j + lanelo;
            #pragma unroll
            for (int i = 0; i < 4; ++i)
                #pragma unroll
                for (int r = 0; r < 4; ++r) {
                    int row = row0 + 64 * wr + 16 * i + 4 * quad + r;
                    Po[(size_t)row * 512 + c] = f2bf(acc[i][j][r]);
                }
        }
        return;
    }

    const int set = col0 >> 9;               // 0=Q,1=K,2=V (tile never straddles)
    const int cbase = (col0 & 511) + 64 * wc;
    if (set == 0) {
        #pragma unroll
        for (int j = 0; j < 4; ++j) {
            int c = cbase + 16 * j + lanelo;
            float vbq = bq[c], vu = pbu[c], vv = pbv[c];
            #pragma unroll
            for (int i = 0; i < 4; ++i)
                #pragma unroll
                for (int r = 0; r < 4; ++r) {
                    int row = row0 + 64 * wr + 16 * i + 4 * quad + r;
                    size_t o = (size_t)row * 512 + c;
                    float aq = acc[i][j][r] + vbq;
                    Qu[o] = f2bf((aq + vu) * KSCALE);
                    Qv[o] = f2bf((aq + vv) * KSCALE);
                }
        }
    } else if (set == 1) {
        #pragma unroll
        for (int j = 0; j < 4; ++j) {
            int c = cbase + 16 * j + lanelo;
            float vbk = bk[c];
            #pragma unroll
            for (int i = 0; i < 4; ++i)
                #pragma unroll
                for (int r = 0; r < 4; ++r) {
                    int row = row0 + 64 * wr + 16 * i + 4 * quad + r;
                    Ko[(size_t)row * 512 + c] = f2bf(acc[i][j][r] + vbk);
                }
        }
    } else {
        const int b_idx = row0 >> 10;
        #pragma unroll
        for (int j = 0; j < 4; ++j) {
            int c = cbase + 16 * j + lanelo;
            int hh = c >> 6, d = c & 63;
            float vbb = bv[c];
            #pragma unroll
            for (int i = 0; i < 4; ++i) {
                int t = (row0 & 1023) + 64 * wr + 16 * i + 4 * quad;
                ushort4 vp;
                vp.x = f2bf(acc[i][j][0] + vbb);
                vp.y = f2bf(acc[i][j][1] + vbb);
                vp.z = f2bf(acc[i][j][2] + vbb);
                vp.w = f2bf(acc[i][j][3] + vbb);
                *(ushort4*)(VoT + ((size_t)((b_idx * 8 + hh) * 64 + d)) * 1024 + t) = vp;
            }
        }
    }
}

// ---------------------------------------------------------------------------
// MFMA flash attention: fused relative shift (banded, register shuffle
// extraction), NO-MAX exp2 softmax (exact; scores bounded, shift-invariant),
// coalesced LDS staging for K / V^T / P-window (the round-5 direct-global
// B-fragments were 64-lane 1KB-stride gathers — 28% slower).
// Block: (64 q-rows, h, b); wave w owns rows [16w,16w+16).
// ---------------------------------------------------------------------------
__global__ __launch_bounds__(256) void attn_mfma(
    const ushort_t* __restrict__ Qu, const ushort_t* __restrict__ Qv,
    const ushort_t* __restrict__ Kb, const ushort_t* __restrict__ VT,
    const ushort_t* __restrict__ Pb,
    ushort_t* __restrict__ AOb)
{
    const int tid = threadIdx.x;
    const int t0 = blockIdx.x * 64;
    const int h  = blockIdx.y;
    const int b  = blockIdx.z;
    const int w = tid >> 6, lane = tid & 63;
    const int quad = lane >> 4, lanelo = lane & 15;
    const int sr = tid >> 2, sc = (tid & 3) * 16;

    __shared__ ushort_t Kt[64][72];     //  9216 B  [s][d]
    __shared__ ushort_t VtT[64][72];    //  9216 B  [d][s]
    __shared__ ushort_t Pt[128][72];    // 18432 B  [j][d]
    __shared__ ushort_t Ps[64][72];     //  9216 B  probs / O staging -> 46080 B

    const size_t qrow = (size_t)(b * T_SEQ + t0 + 16 * w + lanelo) * 512 + h * 64;
    s16x8 qu[2], qv[2];
    qu[0] = *(const s16x8*)(Qu + qrow + quad * 8);
    qu[1] = *(const s16x8*)(Qu + qrow + 32 + quad * 8);
    qv[0] = *(const s16x8*)(Qv + qrow + quad * 8);
    qv[1] = *(const s16x8*)(Qv + qrow + 32 + quad * 8);

    f32x4 acc_o[4] = {};
    float l_part[4] = {0.f, 0.f, 0.f, 0.f};

    const int u_base = lanelo + 63 - 4 * quad;       // u = u_base - r in [48,78]
    const ushort_t* VTbh = VT + ((size_t)((b * 8 + h) * 64)) * 1024;

    const int pr_r = tid >> 1;           // 0..127
    const int pr_c = (tid & 1) * 32;

    for (int s0 = 0; s0 < T_SEQ; s0 += 64) {
        __syncthreads();
        {   // stage K [s][d]
            size_t gk = (size_t)(b * T_SEQ + s0 + sr) * 512 + h * 64 + sc;
            *(s16x8*)&Kt[sr][sc]     = *(const s16x8*)(Kb + gk);
            *(s16x8*)&Kt[sr][sc + 8] = *(const s16x8*)(Kb + gk + 8);
        }
        {   // stage V^T [d][s] from pre-transposed global layout
            const ushort_t* vp = VTbh + (size_t)sr * 1024 + s0 + sc;
            *(s16x8*)&VtT[sr][sc]     = *(const s16x8*)vp;
            *(s16x8*)&VtT[sr][sc + 8] = *(const s16x8*)(vp + 8);
        }
        {   // stage 128-row P window
            const int pr0 = s0 - t0 + 960;           // [0,1920]
            const ushort_t* gp = Pb + (size_t)(pr0 + pr_r) * 512 + h * 64 + pr_c;
            *(s16x8*)&Pt[pr_r][pr_c +  0] = *(const s16x8*)(gp +  0);
            *(s16x8*)&Pt[pr_r][pr_c +  8] = *(const s16x8*)(gp +  8);
            *(s16x8*)&Pt[pr_r][pr_c + 16] = *(const s16x8*)(gp + 16);
            *(s16x8*)&Pt[pr_r][pr_c + 24] = *(const s16x8*)(gp + 24);
        }
        __syncthreads();

        f32x4 acc_c[4] = {};
        f32x4 acc_g[5] = {};
        #pragma unroll
        for (int ks = 0; ks < 2; ++ks) {
            #pragma unroll
            for (int tn = 0; tn < 4; ++tn) {
                s16x8 kf = *(const s16x8*)&Kt[tn * 16 + lanelo][ks * 32 + quad * 8];
                acc_c[tn] = mfma16(qu[ks], kf, acc_c[tn]);
            }
            #pragma unroll
            for (int i = 0; i < 5; ++i) {      // jt = 3 - w + i
                s16x8 pf = *(const s16x8*)&Pt[(3 - w + i) * 16 + lanelo][ks * 32 + quad * 8];
                acc_g[i] = mfma16(qv[ks], pf, acc_g[i]);
            }
        }

        // band extraction + exp2 (no max subtraction; softmax shift-invariant)
        float p[4][4];
        #pragma unroll
        for (int r = 0; r < 4; ++r) {
            int u = u_base - r;
            int srcl = (quad << 4) | (u & 15);
            bool hi = (u >= 64);
            #pragma unroll
            for (int tn = 0; tn < 4; ++tn) {
                float v0 = __shfl(acc_g[tn][r], srcl);
                float v1 = __shfl(acc_g[tn + 1][r], srcl);
                float e = __builtin_amdgcn_exp2f(acc_c[tn][r] + (hi ? v1 : v0));
                p[tn][r] = e;
                l_part[r] += e;
            }
        }
        #pragma unroll
        for (int tn = 0; tn < 4; ++tn)
            #pragma unroll
            for (int r = 0; r < 4; ++r)
                Ps[16 * w + 4 * quad + r][tn * 16 + lanelo] = f2bf(p[tn][r]);
        asm volatile("s_waitcnt lgkmcnt(0)" ::: "memory");

        // PV: A = probs (wave-private Ps rows), B = V^T tile in LDS
        #pragma unroll
        for (int ks = 0; ks < 2; ++ks) {
            s16x8 af = *(const s16x8*)&Ps[16 * w + lanelo][ks * 32 + quad * 8];
            #pragma unroll
            for (int dt = 0; dt < 4; ++dt) {
                s16x8 vb = *(const s16x8*)&VtT[dt * 16 + lanelo][ks * 32 + quad * 8];
                acc_o[dt] = mfma16(af, vb, acc_o[dt]);
            }
        }
    }

    // single end-of-kernel l reduction (16 lanes per row group)
    float inv[4];
    #pragma unroll
    for (int r = 0; r < 4; ++r) {
        float l = l_part[r];
        l += __shfl_xor(l, 1);
        l += __shfl_xor(l, 2);
        l += __shfl_xor(l, 4);
        l += __shfl_xor(l, 8);
        inv[r] = 1.0f / l;
    }

    // epilogue: stage O into Ps (bf16), then coalesced vector stores
    __syncthreads();
    #pragma unroll
    for (int r = 0; r < 4; ++r)
        #pragma unroll
        for (int dt = 0; dt < 4; ++dt)
            Ps[16 * w + 4 * quad + r][dt * 16 + lanelo] = f2bf(acc_o[dt][r] * inv[r]);
    __syncthreads();
    {
        ushort_t* dst = AOb + (size_t)(b * T_SEQ + t0 + sr) * 512 + h * 64 + sc;
        *(s16x8*)dst       = *(const s16x8*)&Ps[sr][sc];
        *(s16x8*)(dst + 8) = *(const s16x8*)&Ps[sr][sc + 8];
    }
}

// ---------------------------------------------------------------------------
// Final projection: out = AOb @ WoT + bo  (A bf16, fp32 out), 128x128 tiles.
// ---------------------------------------------------------------------------
__global__ __launch_bounds__(256) void gemm_out(
    const ushort_t* __restrict__ A, const ushort_t* __restrict__ WTo,
    const float* __restrict__ bias, float* __restrict__ C)
{
    const int tid = threadIdx.x;
    const int col0 = blockIdx.x * 128;
    const int row0 = blockIdx.y * 128;
    const int w = tid >> 6, lane = tid & 63;
    const int quad = lane >> 4, lanelo = lane & 15;
    const int wr = w >> 1, wc = w & 1;
    const int sr = tid >> 1, sc = (tid & 1) * 32;

    __shared__ ushort_t As[128][72];
    __shared__ ushort_t Bs[128][72];

    f32x4 acc[4][4] = {};

    for (int k0 = 0; k0 < 512; k0 += 64) {
        __syncthreads();
        {
            const ushort_t* ap = A + (size_t)(row0 + sr) * 512 + k0 + sc;
            *(s16x8*)&As[sr][sc +  0] = *(const s16x8*)(ap +  0);
            *(s16x8*)&As[sr][sc +  8] = *(const s16x8*)(ap +  8);
            *(s16x8*)&As[sr][sc + 16] = *(const s16x8*)(ap + 16);
            *(s16x8*)&As[sr][sc + 24] = *(const s16x8*)(ap + 24);
            const ushort_t* wp = WTo + (size_t)(col0 + sr) * 512 + k0 + sc;
            *(s16x8*)&Bs[sr][sc +  0] = *(const s16x8*)(wp +  0);
            *(s16x8*)&Bs[sr][sc +  8] = *(const s16x8*)(wp +  8);
            *(s16x8*)&Bs[sr][sc + 16] = *(const s16x8*)(wp + 16);
            *(s16x8*)&Bs[sr][sc + 24] = *(const s16x8*)(wp + 24);
        }
        __syncthreads();

        #pragma unroll
        for (int ks = 0; ks < 2; ++ks) {
            s16x8 af[4], bf[4];
            #pragma unroll
            for (int i = 0; i < 4; ++i)
                af[i] = *(const s16x8*)&As[64 * wr + 16 * i + lanelo][ks * 32 + quad * 8];
            #pragma unroll
            for (int j = 0; j < 4; ++j)
                bf[j] = *(const s16x8*)&Bs[64 * wc + 16 * j + lanelo][ks * 32 + quad * 8];
            #pragma unroll
            for (int i = 0; i < 4; ++i)
                #pragma unroll
                for (int j = 0; j < 4; ++j)
                    acc[i][j] = mfma16(af[i], bf[j], acc[i][j]);
        }
    }

    #pragma unroll
    for (int j = 0; j < 4; ++j) {
        int c = col0 + 64 * wc + 16 * j + lanelo;
        float vb = bias[c];
        #pragma unroll
        for (int i = 0; i < 4; ++i)
            #pragma unroll
            for (int r = 0; r < 4; ++r) {
                int row = row0 + 64 * wr + 16 * i + 4 * quad + r;
                C[(size_t)row * 512 + c] = acc[i][j][r] + vb;
            }
    }
}

// ---------------------------------------------------------------------------
extern "C" void kernel_launch(void* const* d_in, const int* in_sizes, int n_in,
                              void* d_out, int out_size, void* d_ws, size_t ws_size,
                              hipStream_t stream) {
    const float* x       = (const float*)d_in[0];
    const float* pos_enc = (const float*)d_in[1];
    const float* Wq      = (const float*)d_in[2];
    const float* bq      = (const float*)d_in[3];
    const float* Wk      = (const float*)d_in[4];
    const float* bk      = (const float*)d_in[5];
    const float* Wv      = (const float*)d_in[6];
    const float* bv      = (const float*)d_in[7];
    const float* Wpos    = (const float*)d_in[8];
    const float* pbu     = (const float*)d_in[9];
    const float* pbv     = (const float*)d_in[10];
    const float* Wo      = (const float*)d_in[11];
    const float* bo      = (const float*)d_in[12];
    float* out = (float*)d_out;

    const size_t M  = 8 * T_SEQ;                 // 8192
    const size_t SZ = M * D_MODEL;               // 4,194,304

    char* ws = (char*)d_ws;
    ushort_t* xb   = (ushort_t*)ws;              ws += SZ * 2;
    ushort_t* posb = (ushort_t*)ws;              ws += (size_t)2048 * 512 * 2;
    ushort_t* Qu_b = (ushort_t*)ws;              ws += SZ * 2;
    ushort_t* Qv_b = (ushort_t*)ws;              ws += SZ * 2;
    ushort_t* K_b  = (ushort_t*)ws;              ws += SZ * 2;
    ushort_t* VT_b = (ushort_t*)ws;              ws += SZ * 2;
    ushort_t* P_b  = (ushort_t*)ws;              ws += (size_t)2048 * 512 * 2;
    ushort_t* WT   = (ushort_t*)ws;              ws += (size_t)5 * 512 * 512 * 2;
    ushort_t* AOb  = (ushort_t*)ws;              ws += SZ * 2;

    dim3 blk(256);

    hipLaunchKernelGGL(prep, dim3(2880), blk, 0, stream,
                       x, pos_enc, Wq, Wk, Wv, Wpos, Wo, xb, posb, WT);

    hipLaunchKernelGGL(gemm_qkvp, dim3(13, 64), blk, 0, stream,
                       xb, posb, WT, bq, bk, bv, pbu, pbv,
                       Qu_b, Qv_b, K_b, VT_b, P_b);

    hipLaunchKernelGGL(attn_mfma, dim3(16, 8, 8), blk, 0, stream,
                       Qu_b, Qv_b, K_b, VT_b, P_b, AOb);

    hipLaunchKernelGGL(gemm_out, dim3(4, 64), blk, 0, stream,
                       AOb, WT + (size_t)4 * 512 * 512, bo, out);
}

// Round 7
// 239.225 us; speedup vs baseline: 1.2150x; 1.0046x over previous
//
#include <hip/hip_runtime.h>
#include <hip/hip_bf16.h>

#define T_SEQ 1024
#define D_MODEL 512
#define N_HEADS 8
#define D_HEAD 64
// 0.125 (1/sqrt(64)) * log2(e): scores computed directly in exp2 domain
#define KSCALE 0.1803368801111244f

typedef unsigned short ushort_t;
typedef short s16x8 __attribute__((ext_vector_type(8)));
typedef float f32x4 __attribute__((ext_vector_type(4)));

__device__ inline f32x4 mfma16(s16x8 a, s16x8 b, f32x4 c) {
    return __builtin_amdgcn_mfma_f32_16x16x32_bf16(a, b, c, 0, 0, 0);
}

__device__ inline ushort_t f2bf(float f) {   // RTNE float->bf16
    union { float f; unsigned u; } v; v.f = f;
    unsigned r = v.u + 0x7FFFu + ((v.u >> 16) & 1u);
    return (ushort_t)(r >> 16);
}
__device__ inline void cvt4(const float4 f, ushort_t* t) {
    t[0] = f2bf(f.x); t[1] = f2bf(f.y); t[2] = f2bf(f.z); t[3] = f2bf(f.w);
}
__device__ inline s16x8 pack8(const ushort_t* t) {
    s16x8 r;
    #pragma unroll
    for (int e = 0; e < 8; ++e) r[e] = (short)t[e];
    return r;
}

// ---------------------------------------------------------------------------
// prep: blocks [0,2560) cast x->xb + pos->posb (row 2047 zeroed);
//       blocks [2560,2880) transpose+cast the 5 weight matrices into WT.
// ---------------------------------------------------------------------------
__global__ __launch_bounds__(256) void prep(
    const float* __restrict__ x, const float* __restrict__ pos,
    const float* __restrict__ W0, const float* __restrict__ W1,
    const float* __restrict__ W2, const float* __restrict__ W3,
    const float* __restrict__ W4,
    ushort_t* __restrict__ xb, ushort_t* __restrict__ posb,
    ushort_t* __restrict__ WT)
{
    __shared__ float T[64][68];
    const int bx = blockIdx.x;
    const int tid = threadIdx.x;
    if (bx < 2560) {
        const size_t N1 = (size_t)8192 * 512;
        size_t e = ((size_t)bx * 256 + tid) * 8;
        ushort_t tmp[8];
        if (e < N1) {
            const float4* s = (const float4*)(x + e);
            cvt4(s[0], tmp); cvt4(s[1], tmp + 4);
            *(s16x8*)(xb + e) = pack8(tmp);
        } else {
            size_t e2 = e - N1;                 // < 2048*512
            int row = (int)(e2 >> 9);
            if (row < 2047) {
                const float4* s = (const float4*)(pos + e2);
                cvt4(s[0], tmp); cvt4(s[1], tmp + 4);
            } else {
                #pragma unroll
                for (int i = 0; i < 8; ++i) tmp[i] = 0;
            }
            *(s16x8*)(posb + e2) = pack8(tmp);
        }
    } else {
        const int bz = bx - 2560;               // 0..319
        const int z = bz >> 6;                  // 0..4
        const int rem = bz & 63;
        const int n0 = (rem & 7) * 64, k0 = (rem >> 3) * 64;
        const float* W = (z == 0) ? W0 : (z == 1) ? W1
                       : (z == 2) ? W2 : (z == 3) ? W3 : W4;
        const int rr = tid >> 2, cc = (tid & 3) * 16;

        const float* src = W + (size_t)(k0 + rr) * 512 + n0 + cc;
        *(float4*)&T[rr][cc + 0]  = *(const float4*)(src);
        *(float4*)&T[rr][cc + 4]  = *(const float4*)(src + 4);
        *(float4*)&T[rr][cc + 8]  = *(const float4*)(src + 8);
        *(float4*)&T[rr][cc + 12] = *(const float4*)(src + 12);
        __syncthreads();

        ushort_t tmp[16];
        #pragma unroll
        for (int e = 0; e < 16; ++e) tmp[e] = f2bf(T[cc + e][rr]);
        ushort_t* dst = WT + ((size_t)z * 512 + n0 + rr) * 512 + k0 + cc;
        *(s16x8*)dst       = pack8(tmp);
        *(s16x8*)(dst + 8) = pack8(tmp + 8);
    }
}

// ---------------------------------------------------------------------------
// Fused QKV + P GEMM, 128x128 tiles, 4 waves, K=512.
// Grid (13, 64): bx<12 -> qkv (set=col0>>9: Q,K,V); bx==12 -> P GEMM
// (by: row-tile = by>>2 of 16, col-tile = by&3 of 4, M=2048).
// All u16 epilogues re-coalesced through LDS -> b128 global stores.
// ---------------------------------------------------------------------------
__global__ __launch_bounds__(256) void gemm_qkvp(
    const ushort_t* __restrict__ xb, const ushort_t* __restrict__ posb,
    const ushort_t* __restrict__ WT,
    const float* __restrict__ bq, const float* __restrict__ bk,
    const float* __restrict__ bv,
    const float* __restrict__ pbu, const float* __restrict__ pbv,
    ushort_t* __restrict__ Qu, ushort_t* __restrict__ Qv,
    ushort_t* __restrict__ Ko, ushort_t* __restrict__ VoT,
    ushort_t* __restrict__ Po)
{
    const int tid = threadIdx.x;
    const bool is_p = (blockIdx.x == 12);
    int row0, col0;
    const ushort_t* A;
    const ushort_t* B;
    if (is_p) {
        row0 = ((int)blockIdx.y >> 2) * 128;     // 0..1920
        col0 = ((int)blockIdx.y & 3) * 128;      // 0..384
        A = posb;
        B = WT + (size_t)3 * 512 * 512;
    } else {
        row0 = blockIdx.y * 128;
        col0 = blockIdx.x * 128;
        A = xb;
        B = WT;                                  // col0 spans 0..1535 across sets
    }
    const int w = tid >> 6, lane = tid & 63;
    const int quad = lane >> 4, lanelo = lane & 15;
    const int wr = w >> 1, wc = w & 1;
    const int sr = tid >> 1, sc = (tid & 1) * 32;

    __shared__ ushort_t LB[2][128][72];          // As=LB[0], Bs=LB[1]; 36 KB
    ushort_t (*As)[72] = LB[0];
    ushort_t (*Bs)[72] = LB[1];
    ushort_t* SB = &LB[0][0][0];                 // epilogue stage: [128][136] u16

    f32x4 acc[4][4] = {};

    for (int k0 = 0; k0 < 512; k0 += 64) {
        __syncthreads();
        {
            const ushort_t* ap = A + (size_t)(row0 + sr) * 512 + k0 + sc;
            *(s16x8*)&As[sr][sc +  0] = *(const s16x8*)(ap +  0);
            *(s16x8*)&As[sr][sc +  8] = *(const s16x8*)(ap +  8);
            *(s16x8*)&As[sr][sc + 16] = *(const s16x8*)(ap + 16);
            *(s16x8*)&As[sr][sc + 24] = *(const s16x8*)(ap + 24);
            const ushort_t* wp = B + (size_t)(col0 + sr) * 512 + k0 + sc;
            *(s16x8*)&Bs[sr][sc +  0] = *(const s16x8*)(wp +  0);
            *(s16x8*)&Bs[sr][sc +  8] = *(const s16x8*)(wp +  8);
            *(s16x8*)&Bs[sr][sc + 16] = *(const s16x8*)(wp + 16);
            *(s16x8*)&Bs[sr][sc + 24] = *(const s16x8*)(wp + 24);
        }
        __syncthreads();

        #pragma unroll
        for (int ks = 0; ks < 2; ++ks) {
            s16x8 af[4], bf[4];
            #pragma unroll
            for (int i = 0; i < 4; ++i)
                af[i] = *(const s16x8*)&As[64 * wr + 16 * i + lanelo][ks * 32 + quad * 8];
            #pragma unroll
            for (int j = 0; j < 4; ++j)
                bf[j] = *(const s16x8*)&Bs[64 * wc + 16 * j + lanelo][ks * 32 + quad * 8];
            #pragma unroll
            for (int i = 0; i < 4; ++i)
                #pragma unroll
                for (int j = 0; j < 4; ++j)
                    acc[i][j] = mfma16(af[i], bf[j], acc[i][j]);
        }
    }

    // ---- epilogue: stage bf16 into SB [128][136], store 8 x b128/thread ----
    const int orow = tid >> 1, ocol = (tid & 1) * 64;
    const ushort_t* srcp = SB + orow * 136 + ocol;

    if (is_p) {
        __syncthreads();
        #pragma unroll
        for (int j = 0; j < 4; ++j)
            #pragma unroll
            for (int i = 0; i < 4; ++i)
                #pragma unroll
                for (int r = 0; r < 4; ++r)
                    SB[(64 * wr + 16 * i + 4 * quad + r) * 136 + 64 * wc + 16 * j + lanelo]
                        = f2bf(acc[i][j][r]);
        __syncthreads();
        ushort_t* dstp = Po + (size_t)(row0 + orow) * 512 + col0 + ocol;
        #pragma unroll
        for (int v = 0; v < 8; ++v)
            *(s16x8*)(dstp + 8 * v) = *(const s16x8*)(srcp + 8 * v);
        return;
    }

    const int set = col0 >> 9;               // 0=Q,1=K,2=V (tile never straddles)
    const int cb0 = col0 & 511;              // column base within the 512-wide set
    const int cbase = cb0 + 64 * wc;

    if (set == 0) {
        // round A: Qu
        __syncthreads();
        #pragma unroll
        for (int j = 0; j < 4; ++j) {
            int c = cbase + 16 * j + lanelo;
            float vq = bq[c] + pbu[c];
            #pragma unroll
            for (int i = 0; i < 4; ++i)
                #pragma unroll
                for (int r = 0; r < 4; ++r)
                    SB[(64 * wr + 16 * i + 4 * quad + r) * 136 + 64 * wc + 16 * j + lanelo]
                        = f2bf((acc[i][j][r] + vq) * KSCALE);
        }
        __syncthreads();
        {
            ushort_t* dstp = Qu + (size_t)(row0 + orow) * 512 + cb0 + ocol;
            #pragma unroll
            for (int v = 0; v < 8; ++v)
                *(s16x8*)(dstp + 8 * v) = *(const s16x8*)(srcp + 8 * v);
        }
        // round B: Qv
        __syncthreads();
        #pragma unroll
        for (int j = 0; j < 4; ++j) {
            int c = cbase + 16 * j + lanelo;
            float vq = bq[c] + pbv[c];
            #pragma unroll
            for (int i = 0; i < 4; ++i)
                #pragma unroll
                for (int r = 0; r < 4; ++r)
                    SB[(64 * wr + 16 * i + 4 * quad + r) * 136 + 64 * wc + 16 * j + lanelo]
                        = f2bf((acc[i][j][r] + vq) * KSCALE);
        }
        __syncthreads();
        {
            ushort_t* dstp = Qv + (size_t)(row0 + orow) * 512 + cb0 + ocol;
            #pragma unroll
            for (int v = 0; v < 8; ++v)
                *(s16x8*)(dstp + 8 * v) = *(const s16x8*)(srcp + 8 * v);
        }
    } else if (set == 1) {
        __syncthreads();
        #pragma unroll
        for (int j = 0; j < 4; ++j) {
            int c = cbase + 16 * j + lanelo;
            float vbk = bk[c];
            #pragma unroll
            for (int i = 0; i < 4; ++i)
                #pragma unroll
                for (int r = 0; r < 4; ++r)
                    SB[(64 * wr + 16 * i + 4 * quad + r) * 136 + 64 * wc + 16 * j + lanelo]
                        = f2bf(acc[i][j][r] + vbk);
        }
        __syncthreads();
        ushort_t* dstp = Ko + (size_t)(row0 + orow) * 512 + cb0 + ocol;
        #pragma unroll
        for (int v = 0; v < 8; ++v)
            *(s16x8*)(dstp + 8 * v) = *(const s16x8*)(srcp + 8 * v);
    } else {
        // V: stage TRANSPOSED (SB[col][t_local]) so VoT gets b128 along t
        __syncthreads();
        #pragma unroll
        for (int j = 0; j < 4; ++j) {
            int c = cbase + 16 * j + lanelo;
            float vbb = bv[c];
            #pragma unroll
            for (int i = 0; i < 4; ++i)
                #pragma unroll
                for (int r = 0; r < 4; ++r)
                    SB[(64 * wc + 16 * j + lanelo) * 136 + 64 * wr + 16 * i + 4 * quad + r]
                        = f2bf(acc[i][j][r] + vbb);
        }
        __syncthreads();
        const int b_idx = row0 >> 10;
        const int tb0 = row0 & 1023;
        const int c = cb0 + orow;                // V column 0..511
        const int hh = c >> 6, d = c & 63;
        ushort_t* dstp = VoT + ((size_t)((b_idx * 8 + hh) * 64 + d)) * 1024 + tb0 + ocol;
        #pragma unroll
        for (int v = 0; v < 8; ++v)
            *(s16x8*)(dstp + 8 * v) = *(const s16x8*)(srcp + 8 * v);
    }
}

// ---------------------------------------------------------------------------
// MFMA flash attention: fused relative shift (banded, register shuffle
// extraction), no-max exp2 softmax, coalesced LDS staging, CIRCULAR 128-slot
// P window (stages only 64 new rows/iter), register-prefetch pipeline
// (next iter's K/VT/P loads issued before compute, committed after barrier).
// Block: (64 q-rows, h, b); wave w owns rows [16w,16w+16).
// ---------------------------------------------------------------------------
__global__ __launch_bounds__(256) void attn_mfma(
    const ushort_t* __restrict__ Qu, const ushort_t* __restrict__ Qv,
    const ushort_t* __restrict__ Kb, const ushort_t* __restrict__ VT,
    const ushort_t* __restrict__ Pb,
    ushort_t* __restrict__ AOb)
{
    const int tid = threadIdx.x;
    const int t0 = blockIdx.x * 64;
    const int h  = blockIdx.y;
    const int b  = blockIdx.z;
    const int w = tid >> 6, lane = tid & 63;
    const int quad = lane >> 4, lanelo = lane & 15;
    const int sr = tid >> 2, sc = (tid & 3) * 16;

    __shared__ ushort_t Kt[64][72];     //  9216 B  [s][d]
    __shared__ ushort_t VtT[64][72];    //  9216 B  [d][s]
    __shared__ ushort_t Pt[128][72];    // 18432 B  circular, slot = row & 127
    __shared__ ushort_t Ps[64][72];     //  9216 B  probs / O staging -> 46080 B

    const size_t qrow = (size_t)(b * T_SEQ + t0 + 16 * w + lanelo) * 512 + h * 64;
    s16x8 qu[2], qv[2];
    qu[0] = *(const s16x8*)(Qu + qrow + quad * 8);
    qu[1] = *(const s16x8*)(Qu + qrow + 32 + quad * 8);
    qv[0] = *(const s16x8*)(Qv + qrow + quad * 8);
    qv[1] = *(const s16x8*)(Qv + qrow + 32 + quad * 8);

    f32x4 acc_o[4] = {};
    float l_part[4] = {0.f, 0.f, 0.f, 0.f};

    const int u_base = lanelo + 63 - 4 * quad;       // u = u_base - r in [48,78]
    const ushort_t* VTbh = VT + ((size_t)((b * 8 + h) * 64)) * 1024;
    const ushort_t* Kbh  = Kb + (size_t)b * T_SEQ * 512 + (size_t)h * 64;
    const int pr_base = 960 - t0;                    // window start at s0=0

    // ---- prologue: stage iter-0 K, V^T, and full 128-row P window ----
    {
        size_t gk = (size_t)(t0 * 0 + sr) * 512;     // s0 = 0
        const ushort_t* kp = Kbh + (size_t)sr * 512 + sc;
        *(s16x8*)&Kt[sr][sc]     = *(const s16x8*)kp;
        *(s16x8*)&Kt[sr][sc + 8] = *(const s16x8*)(kp + 8);
        const ushort_t* vp = VTbh + (size_t)sr * 1024 + sc;
        *(s16x8*)&VtT[sr][sc]     = *(const s16x8*)vp;
        *(s16x8*)&VtT[sr][sc + 8] = *(const s16x8*)(vp + 8);
        const int pr_r = tid >> 1, pr_c = (tid & 1) * 32;
        const int slot = (pr_base + pr_r) & 127;
        const ushort_t* gp = Pb + (size_t)(pr_base + pr_r) * 512 + h * 64 + pr_c;
        *(s16x8*)&Pt[slot][pr_c +  0] = *(const s16x8*)(gp +  0);
        *(s16x8*)&Pt[slot][pr_c +  8] = *(const s16x8*)(gp +  8);
        *(s16x8*)&Pt[slot][pr_c + 16] = *(const s16x8*)(gp + 16);
        *(s16x8*)&Pt[slot][pr_c + 24] = *(const s16x8*)(gp + 24);
        (void)gk;
    }

    for (int it = 0; it < 16; ++it) {
        const int s0 = it * 64;
        __syncthreads();                 // staged data visible

        // ---- prefetch next iter into registers (VMEM overlaps compute) ----
        s16x8 kp0, kp1, vp0, vp1, pp0, pp1;
        const bool more = (it < 15);
        if (more) {
            const ushort_t* kp = Kbh + (size_t)(s0 + 64 + sr) * 512 + sc;
            kp0 = *(const s16x8*)kp;
            kp1 = *(const s16x8*)(kp + 8);
            const ushort_t* vp = VTbh + (size_t)sr * 1024 + s0 + 64 + sc;
            vp0 = *(const s16x8*)vp;
            vp1 = *(const s16x8*)(vp + 8);
            const ushort_t* gp = Pb + (size_t)(pr_base + s0 + 128 + sr) * 512 + h * 64 + sc;
            pp0 = *(const s16x8*)gp;
            pp1 = *(const s16x8*)(gp + 8);
        }

        // ---- compute ----
        const int pbase = (pr_base + s0) & 127;
        f32x4 acc_c[4] = {};
        f32x4 acc_g[5] = {};
        #pragma unroll
        for (int ks = 0; ks < 2; ++ks) {
            #pragma unroll
            for (int tn = 0; tn < 4; ++tn) {
                s16x8 kf = *(const s16x8*)&Kt[tn * 16 + lanelo][ks * 32 + quad * 8];
                acc_c[tn] = mfma16(qu[ks], kf, acc_c[tn]);
            }
            #pragma unroll
            for (int i = 0; i < 5; ++i) {      // jt = 3 - w + i
                int prow = (pbase + (3 - w + i) * 16 + lanelo) & 127;
                s16x8 pf = *(const s16x8*)&Pt[prow][ks * 32 + quad * 8];
                acc_g[i] = mfma16(qv[ks], pf, acc_g[i]);
            }
        }

        // band extraction + exp2 (no max subtraction; softmax shift-invariant)
        float p[4][4];
        #pragma unroll
        for (int r = 0; r < 4; ++r) {
            int u = u_base - r;
            int srcl = (quad << 4) | (u & 15);
            bool hi = (u >= 64);
            #pragma unroll
            for (int tn = 0; tn < 4; ++tn) {
                float v0 = __shfl(acc_g[tn][r], srcl);
                float v1 = __shfl(acc_g[tn + 1][r], srcl);
                float e = __builtin_amdgcn_exp2f(acc_c[tn][r] + (hi ? v1 : v0));
                p[tn][r] = e;
                l_part[r] += e;
            }
        }
        #pragma unroll
        for (int tn = 0; tn < 4; ++tn)
            #pragma unroll
            for (int r = 0; r < 4; ++r)
                Ps[16 * w + 4 * quad + r][tn * 16 + lanelo] = f2bf(p[tn][r]);
        asm volatile("s_waitcnt lgkmcnt(0)" ::: "memory");

        // PV: A = probs (wave-private Ps rows), B = V^T tile in LDS
        #pragma unroll
        for (int ks = 0; ks < 2; ++ks) {
            s16x8 af = *(const s16x8*)&Ps[16 * w + lanelo][ks * 32 + quad * 8];
            #pragma unroll
            for (int dt = 0; dt < 4; ++dt) {
                s16x8 vb = *(const s16x8*)&VtT[dt * 16 + lanelo][ks * 32 + quad * 8];
                acc_o[dt] = mfma16(af, vb, acc_o[dt]);
            }
        }

        __syncthreads();                 // compute done before LDS overwrite
        if (more) {
            *(s16x8*)&Kt[sr][sc]      = kp0;
            *(s16x8*)&Kt[sr][sc + 8]  = kp1;
            *(s16x8*)&VtT[sr][sc]     = vp0;
            *(s16x8*)&VtT[sr][sc + 8] = vp1;
            const int slot = (pr_base + s0 + 128 + sr) & 127;
            *(s16x8*)&Pt[slot][sc]     = pp0;
            *(s16x8*)&Pt[slot][sc + 8] = pp1;
        }
    }

    // single end-of-kernel l reduction (16 lanes per row group)
    float inv[4];
    #pragma unroll
    for (int r = 0; r < 4; ++r) {
        float l = l_part[r];
        l += __shfl_xor(l, 1);
        l += __shfl_xor(l, 2);
        l += __shfl_xor(l, 4);
        l += __shfl_xor(l, 8);
        inv[r] = 1.0f / l;
    }

    // epilogue: stage O into Ps (bf16), then coalesced vector stores
    __syncthreads();
    #pragma unroll
    for (int r = 0; r < 4; ++r)
        #pragma unroll
        for (int dt = 0; dt < 4; ++dt)
            Ps[16 * w + 4 * quad + r][dt * 16 + lanelo] = f2bf(acc_o[dt][r] * inv[r]);
    __syncthreads();
    {
        ushort_t* dst = AOb + (size_t)(b * T_SEQ + t0 + sr) * 512 + h * 64 + sc;
        *(s16x8*)dst       = *(const s16x8*)&Ps[sr][sc];
        *(s16x8*)(dst + 8) = *(const s16x8*)&Ps[sr][sc + 8];
    }
}

// ---------------------------------------------------------------------------
// Final projection: out = AOb @ WoT + bo  (A bf16, fp32 out), 128x128 tiles.
// ---------------------------------------------------------------------------
__global__ __launch_bounds__(256) void gemm_out(
    const ushort_t* __restrict__ A, const ushort_t* __restrict__ WTo,
    const float* __restrict__ bias, float* __restrict__ C)
{
    const int tid = threadIdx.x;
    const int col0 = blockIdx.x * 128;
    const int row0 = blockIdx.y * 128;
    const int w = tid >> 6, lane = tid & 63;
    const int quad = lane >> 4, lanelo = lane & 15;
    const int wr = w >> 1, wc = w & 1;
    const int sr = tid >> 1, sc = (tid & 1) * 32;

    __shared__ ushort_t As[128][72];
    __shared__ ushort_t Bs[128][72];

    f32x4 acc[4][4] = {};

    for (int k0 = 0; k0 < 512; k0 += 64) {
        __syncthreads();
        {
            const ushort_t* ap = A + (size_t)(row0 + sr) * 512 + k0 + sc;
            *(s16x8*)&As[sr][sc +  0] = *(const s16x8*)(ap +  0);
            *(s16x8*)&As[sr][sc +  8] = *(const s16x8*)(ap +  8);
            *(s16x8*)&As[sr][sc + 16] = *(const s16x8*)(ap + 16);
            *(s16x8*)&As[sr][sc + 24] = *(const s16x8*)(ap + 24);
            const ushort_t* wp = WTo + (size_t)(col0 + sr) * 512 + k0 + sc;
            *(s16x8*)&Bs[sr][sc +  0] = *(const s16x8*)(wp +  0);
            *(s16x8*)&Bs[sr][sc +  8] = *(const s16x8*)(wp +  8);
            *(s16x8*)&Bs[sr][sc + 16] = *(const s16x8*)(wp + 16);
            *(s16x8*)&Bs[sr][sc + 24] = *(const s16x8*)(wp + 24);
        }
        __syncthreads();

        #pragma unroll
        for (int ks = 0; ks < 2; ++ks) {
            s16x8 af[4], bf[4];
            #pragma unroll
            for (int i = 0; i < 4; ++i)
                af[i] = *(const s16x8*)&As[64 * wr + 16 * i + lanelo][ks * 32 + quad * 8];
            #pragma unroll
            for (int j = 0; j < 4; ++j)
                bf[j] = *(const s16x8*)&Bs[64 * wc + 16 * j + lanelo][ks * 32 + quad * 8];
            #pragma unroll
            for (int i = 0; i < 4; ++i)
                #pragma unroll
                for (int j = 0; j < 4; ++j)
                    acc[i][j] = mfma16(af[i], bf[j], acc[i][j]);
        }
    }

    #pragma unroll
    for (int j = 0; j < 4; ++j) {
        int c = col0 + 64 * wc + 16 * j + lanelo;
        float vb = bias[c];
        #pragma unroll
        for (int i = 0; i < 4; ++i)
            #pragma unroll
            for (int r = 0; r < 4; ++r) {
                int row = row0 + 64 * wr + 16 * i + 4 * quad + r;
                C[(size_t)row * 512 + c] = acc[i][j][r] + vb;
            }
    }
}

// ---------------------------------------------------------------------------
extern "C" void kernel_launch(void* const* d_in, const int* in_sizes, int n_in,
                              void* d_out, int out_size, void* d_ws, size_t ws_size,
                              hipStream_t stream) {
    const float* x       = (const float*)d_in[0];
    const float* pos_enc = (const float*)d_in[1];
    const float* Wq      = (const float*)d_in[2];
    const float* bq      = (const float*)d_in[3];
    const float* Wk      = (const float*)d_in[4];
    const float* bk      = (const float*)d_in[5];
    const float* Wv      = (const float*)d_in[6];
    const float* bv      = (const float*)d_in[7];
    const float* Wpos    = (const float*)d_in[8];
    const float* pbu     = (const float*)d_in[9];
    const float* pbv     = (const float*)d_in[10];
    const float* Wo      = (const float*)d_in[11];
    const float* bo      = (const float*)d_in[12];
    float* out = (float*)d_out;

    const size_t M  = 8 * T_SEQ;                 // 8192
    const size_t SZ = M * D_MODEL;               // 4,194,304

    char* ws = (char*)d_ws;
    ushort_t* xb   = (ushort_t*)ws;              ws += SZ * 2;
    ushort_t* posb = (ushort_t*)ws;              ws += (size_t)2048 * 512 * 2;
    ushort_t* Qu_b = (ushort_t*)ws;              ws += SZ * 2;
    ushort_t* Qv_b = (ushort_t*)ws;              ws += SZ * 2;
    ushort_t* K_b  = (ushort_t*)ws;              ws += SZ * 2;
    ushort_t* VT_b = (ushort_t*)ws;              ws += SZ * 2;
    ushort_t* P_b  = (ushort_t*)ws;              ws += (size_t)2048 * 512 * 2;
    ushort_t* WT   = (ushort_t*)ws;              ws += (size_t)5 * 512 * 512 * 2;
    ushort_t* AOb  = (ushort_t*)ws;              ws += SZ * 2;

    dim3 blk(256);

    hipLaunchKernelGGL(prep, dim3(2880), blk, 0, stream,
                       x, pos_enc, Wq, Wk, Wv, Wpos, Wo, xb, posb, WT);

    hipLaunchKernelGGL(gemm_qkvp, dim3(13, 64), blk, 0, stream,
                       xb, posb, WT, bq, bk, bv, pbu, pbv,
                       Qu_b, Qv_b, K_b, VT_b, P_b);

    hipLaunchKernelGGL(attn_mfma, dim3(16, 8, 8), blk, 0, stream,
                       Qu_b, Qv_b, K_b, VT_b, P_b, AOb);

    hipLaunchKernelGGL(gemm_out, dim3(4, 64), blk, 0, stream,
                       AOb, WT + (size_t)4 * 512 * 512, bo, out);
}